// Round 1
// baseline (112.428 us; speedup 1.0000x reference)
//
#include <hip/hip_runtime.h>
#include <math.h>

#define B_   128
#define H_   192
#define W_   192
#define NC_  5
#define HW_  (H_*W_)
#define NPTS 9
#define EPS_ 1e-8f

struct LinvT { float m[12][NPTS]; };

// ---------------- Kernel 1: class_aware_mixup (vectorized float4/int4) ----------------
__global__ __launch_bounds__(256) void mixup_kernel(
    const float* __restrict__ x, const int* __restrict__ masks,
    const float* __restrict__ lam_p, const int* __restrict__ perm,
    float* __restrict__ mixed)
{
    int idx = blockIdx.x * 256 + threadIdx.x;
    const int total4 = B_ * HW_ / 4;
    if (idx >= total4) return;
    float lam = lam_p[0];
    int b  = idx / (HW_ / 4);
    int p4 = (idx - b * (HW_ / 4)) * 4;
    const float4 xv = *reinterpret_cast<const float4*>(x + (size_t)b * HW_ + p4);
    int pb = perm[b];
    const float4 xp = *reinterpret_cast<const float4*>(x + (size_t)pb * HW_ + p4);

    int ma[NC_][4];
    #pragma unroll
    for (int c = 0; c < NC_; ++c) {
        int4 mv = *reinterpret_cast<const int4*>(masks + ((size_t)b * NC_ + c) * HW_ + p4);
        ma[c][0] = mv.x; ma[c][1] = mv.y; ma[c][2] = mv.z; ma[c][3] = mv.w;
    }
    float xa[4]  = {xv.x, xv.y, xv.z, xv.w};
    float xpa[4] = {xp.x, xp.y, xp.z, xp.w};
    float outv[4];
    #pragma unroll
    for (int l = 0; l < 4; ++l) {
        int s = 0, fg = 0;
        #pragma unroll
        for (int c = 0; c < NC_; ++c) { int m = ma[c][l]; s += m; fg += (m == 1); }
        float bg = (s == 0) ? 1.f : 0.f;
        outv[l] = bg * xa[l] + (float)fg * (lam * xa[l] + (1.f - lam) * xpa[l]);
    }
    *reinterpret_cast<float4*>(mixed + (size_t)b * HW_ + p4) =
        make_float4(outv[0], outv[1], outv[2], outv[3]);
}

// ---------------- Kernel 2: point_elasticity ----------------
__global__ void elas_kernel(const int* __restrict__ masks, float* __restrict__ elas)
{
    const float ETAB[5] = {0.05f, 0.12f, 0.08f, 0.15f, 0.1f};
    int b = blockIdx.x;
    int t = threadIdx.x;
    if (t >= NPTS) return;
    int i = t / 3, j = t % 3;
    int yc = (i * (H_ - 1)) / 2;   // matches int(i/2*(H-1)) for i in {0,1,2}
    int xc = (j * (W_ - 1)) / 2;
    int y0 = yc - 2 < 0 ? 0 : yc - 2;
    int y1 = yc + 3 > H_ ? H_ : yc + 3;
    int x0 = xc - 2 < 0 ? 0 : xc - 2;
    int x1 = xc + 3 > W_ ? W_ : xc + 3;
    int best = -1, best_c = 0;
    for (int c = 0; c < NC_; ++c) {
        int s = 0;
        for (int y = y0; y < y1; ++y)
            for (int xx = x0; xx < x1; ++xx)
                s += masks[((size_t)b * NC_ + c) * HW_ + y * W_ + xx];
        if (s > best) { best = s; best_c = c; }   // strict > keeps first max (jnp.argmax)
    }
    elas[b * NPTS + t] = ETAB[best_c];
}

// ---------------- Kernel 3: TPS weights via precomputed L^-1 ----------------
__global__ void solve_kernel(const float* __restrict__ elas,
                             const float* __restrict__ ng,
                             const float* __restrict__ nl,
                             LinvT Linv, float* __restrict__ wts)
{
    int tid = blockIdx.x * 64 + threadIdx.x;
    if (tid >= 2 * B_) return;
    int t = tid / B_, b = tid - t * B_;
    const float* noise = (t == 0) ? ng : nl;
    float disp[NPTS][2];
    #pragma unroll
    for (int k = 0; k < NPTS; ++k) {
        float e = elas[b * NPTS + k];
        disp[k][0] = noise[((size_t)b * NPTS + k) * 2 + 0] * e;
        disp[k][1] = noise[((size_t)b * NPTS + k) * 2 + 1] * e;
    }
    #pragma unroll
    for (int c = 0; c < 2; ++c) {
        float nb = (disp[1][c] + disp[7][c] + disp[3][c] + disp[5][c]) * 0.25f;
        disp[4][c] = 0.8f * disp[4][c] + 0.2f * nb;
    }
    float dst[NPTS][2];
    #pragma unroll
    for (int k = 0; k < NPTS; ++k) {
        dst[k][0] = (float)(k / 3 - 1) + disp[k][0];
        dst[k][1] = (float)(k % 3 - 1) + disp[k][1];
    }
    float* wout = wts + (size_t)tid * 24;
    #pragma unroll
    for (int r = 0; r < 12; ++r) {
        float a0 = 0.f, a1 = 0.f;
        #pragma unroll
        for (int k = 0; k < NPTS; ++k) {
            a0 += Linv.m[r][k] * dst[k][0];
            a1 += Linv.m[r][k] * dst[k][1];
        }
        wout[r * 2 + 0] = a0;
        wout[r * 2 + 1] = a1;
    }
}

// ---------------- Kernel 4: TPS warp + bilinear (zero pad, align_corners) ----------------
__device__ __forceinline__ float tap_val(int t, int b, int y, int xx,
    const float* __restrict__ x, const float* __restrict__ mixed,
    const int* __restrict__ masks, float lam, int pb, int fused)
{
    if (y < 0 || y > H_ - 1 || xx < 0 || xx > W_ - 1) return 0.f;
    size_t off = (size_t)y * W_ + xx;
    if (t == 1) return x[(size_t)b * HW_ + off];
    if (!fused) return mixed[(size_t)b * HW_ + off];
    // fused mixup recompute (fallback when ws too small)
    float xv  = x[(size_t)b * HW_ + off];
    float xpv = x[(size_t)pb * HW_ + off];
    int s = 0, fg = 0;
    #pragma unroll
    for (int c = 0; c < NC_; ++c) {
        int m = masks[((size_t)b * NC_ + c) * HW_ + off];
        s += m; fg += (m == 1);
    }
    float bg = (s == 0) ? 1.f : 0.f;
    return bg * xv + (float)fg * (lam * xv + (1.f - lam) * xpv);
}

__global__ __launch_bounds__(256) void warp_kernel(
    const float* __restrict__ x, const float* __restrict__ mixed,
    const float* __restrict__ wts, float* __restrict__ out,
    const int* __restrict__ masks, const float* __restrict__ lam_p,
    const int* __restrict__ perm, int fused)
{
    int idx = blockIdx.x * 256 + threadIdx.x;
    if (idx >= 2 * B_ * HW_) return;
    int t   = idx / (B_ * HW_);
    int rem = idx - t * (B_ * HW_);
    int b   = rem / HW_;
    int p   = rem - b * HW_;
    int h   = p / W_;
    int wpx = p - h * W_;

    const float* wt = wts + ((size_t)t * B_ + b) * 24;
    float px = -1.f + 2.f * (float)wpx / (float)(W_ - 1);
    float py = -1.f + 2.f * (float)h   / (float)(H_ - 1);

    float gx = wt[18] + px * wt[20] + py * wt[22];
    float gy = wt[19] + px * wt[21] + py * wt[23];
    #pragma unroll
    for (int k = 0; k < NPTS; ++k) {
        float cx = (float)(k / 3 - 1);
        float cy = (float)(k % 3 - 1);
        float dx = px - cx, dy = py - cy;
        float d2 = dx * dx + dy * dy;
        float u = 0.5f * d2 * logf(d2 + EPS_);
        gx += u * wt[k * 2 + 0];
        gy += u * wt[k * 2 + 1];
    }

    float ix = (gx + 1.f) * 0.5f * (float)(W_ - 1);
    float iy = (gy + 1.f) * 0.5f * (float)(H_ - 1);
    float x0f = floorf(ix), y0f = floorf(iy);
    float wx1 = ix - x0f, wx0 = 1.f - wx1;
    float wy1 = iy - y0f, wy0 = 1.f - wy1;
    int x0 = (int)x0f, y0 = (int)y0f;

    float lam = lam_p[0];
    int pb = perm[b];
    float v00 = tap_val(t, b, y0,     x0,     x, mixed, masks, lam, pb, fused);
    float v01 = tap_val(t, b, y0,     x0 + 1, x, mixed, masks, lam, pb, fused);
    float v10 = tap_val(t, b, y0 + 1, x0,     x, mixed, masks, lam, pb, fused);
    float v11 = tap_val(t, b, y0 + 1, x0 + 1, x, mixed, masks, lam, pb, fused);

    out[idx] = v00 * (wy0 * wx0) + v01 * (wy0 * wx1) + v10 * (wy1 * wx0) + v11 * (wy1 * wx1);
}

// ---------------- Host: build constant L^-1 (first 9 columns) in double ----------------
static void build_linv(LinvT* out)
{
    double srcp[NPTS][2];
    for (int k = 0; k < NPTS; ++k) {
        srcp[k][0] = (double)(k / 3) - 1.0;
        srcp[k][1] = (double)(k % 3) - 1.0;
    }
    double A[12][24];
    for (int r = 0; r < 12; ++r)
        for (int c = 0; c < 24; ++c) A[r][c] = 0.0;
    for (int i = 0; i < NPTS; ++i) {
        for (int j = 0; j < NPTS; ++j) {
            double dx = srcp[i][0] - srcp[j][0];
            double dy = srcp[i][1] - srcp[j][1];
            double d2 = dx * dx + dy * dy;
            A[i][j] = 0.5 * d2 * log(d2 + 1e-8);
        }
        A[i][9]  = 1.0; A[i][10] = srcp[i][0]; A[i][11] = srcp[i][1];
        A[9][i]  = 1.0; A[10][i] = srcp[i][0]; A[11][i] = srcp[i][1];
    }
    for (int r = 0; r < 12; ++r) A[r][12 + r] = 1.0;
    // Gauss-Jordan with partial pivoting
    for (int col = 0; col < 12; ++col) {
        int piv = col; double mx = fabs(A[col][col]);
        for (int r = col + 1; r < 12; ++r)
            if (fabs(A[r][col]) > mx) { mx = fabs(A[r][col]); piv = r; }
        if (piv != col)
            for (int c = 0; c < 24; ++c) { double tmp = A[col][c]; A[col][c] = A[piv][c]; A[piv][c] = tmp; }
        double d = A[col][col];
        for (int c = 0; c < 24; ++c) A[col][c] /= d;
        for (int r = 0; r < 12; ++r) {
            if (r == col) continue;
            double f = A[r][col];
            if (f != 0.0)
                for (int c = 0; c < 24; ++c) A[r][c] -= f * A[col][c];
        }
    }
    for (int r = 0; r < 12; ++r)
        for (int k = 0; k < NPTS; ++k)
            out->m[r][k] = (float)A[r][12 + k];
}

extern "C" void kernel_launch(void* const* d_in, const int* in_sizes, int n_in,
                              void* d_out, int out_size, void* d_ws, size_t ws_size,
                              hipStream_t stream)
{
    (void)in_sizes; (void)n_in; (void)out_size;
    const float* x     = (const float*)d_in[0];
    const int*   masks = (const int*)d_in[1];
    const float* lam   = (const float*)d_in[2];
    const int*   perm  = (const int*)d_in[3];
    const float* ng    = (const float*)d_in[4];
    const float* nl    = (const float*)d_in[5];
    float* out = (float*)d_out;

    char* ws = (char*)d_ws;
    float* elas  = (float*)ws;              // 128*9*4   = 4608 B
    float* wts   = (float*)(ws + 8192);     // 2*128*24*4 = 24576 B
    float* mixed = (float*)(ws + 40960);    // B*HW*4    = 18.9 MB
    size_t need = 40960 + (size_t)B_ * HW_ * sizeof(float);
    int fused = (ws_size < need) ? 1 : 0;

    LinvT Linv;
    build_linv(&Linv);

    if (!fused) {
        int total4 = B_ * HW_ / 4;
        mixup_kernel<<<(total4 + 255) / 256, 256, 0, stream>>>(x, masks, lam, perm, mixed);
    }
    elas_kernel<<<B_, 64, 0, stream>>>(masks, elas);
    solve_kernel<<<(2 * B_ + 63) / 64, 64, 0, stream>>>(elas, ng, nl, Linv, wts);
    int total = 2 * B_ * HW_;
    warp_kernel<<<(total + 255) / 256, 256, 0, stream>>>(x, mixed, wts, out, masks, lam, perm, fused);
}

// Round 2
// 72.662 us; speedup vs baseline: 1.5473x; 1.5473x over previous
//
#include <hip/hip_runtime.h>
#include <math.h>

#define B_   128
#define H_   192
#define W_   192
#define NC_  5
#define HW_  (H_*W_)
#define NPTS 9
#define EPS_ 1e-8f
#define CHUNK 16   // (t,b) combos per block in warp kernel; 256/CHUNK grid.y

struct LinvT { float m[12][NPTS]; };

// ---------------- Kernel 1: class_aware_mixup (vectorized float4/int4) ----------------
__global__ __launch_bounds__(256) void mixup_kernel(
    const float* __restrict__ x, const int* __restrict__ masks,
    const float* __restrict__ lam_p, const int* __restrict__ perm,
    float* __restrict__ mixed)
{
    int idx = blockIdx.x * 256 + threadIdx.x;
    const int total4 = B_ * HW_ / 4;
    if (idx >= total4) return;
    float lam = lam_p[0];
    int b  = idx / (HW_ / 4);
    int p4 = (idx - b * (HW_ / 4)) * 4;
    const float4 xv = *reinterpret_cast<const float4*>(x + (size_t)b * HW_ + p4);
    int pb = perm[b];
    const float4 xp = *reinterpret_cast<const float4*>(x + (size_t)pb * HW_ + p4);

    int ma[NC_][4];
    #pragma unroll
    for (int c = 0; c < NC_; ++c) {
        int4 mv = *reinterpret_cast<const int4*>(masks + ((size_t)b * NC_ + c) * HW_ + p4);
        ma[c][0] = mv.x; ma[c][1] = mv.y; ma[c][2] = mv.z; ma[c][3] = mv.w;
    }
    float xa[4]  = {xv.x, xv.y, xv.z, xv.w};
    float xpa[4] = {xp.x, xp.y, xp.z, xp.w};
    float outv[4];
    #pragma unroll
    for (int l = 0; l < 4; ++l) {
        int s = 0, fg = 0;
        #pragma unroll
        for (int c = 0; c < NC_; ++c) { int m = ma[c][l]; s += m; fg += (m == 1); }
        float bg = (s == 0) ? 1.f : 0.f;
        outv[l] = bg * xa[l] + (float)fg * (lam * xa[l] + (1.f - lam) * xpa[l]);
    }
    *reinterpret_cast<float4*>(mixed + (size_t)b * HW_ + p4) =
        make_float4(outv[0], outv[1], outv[2], outv[3]);
}

// ---------------- Kernel 2: point_elasticity (45 parallel region-sums + LDS argmax) ----
__global__ void elas_kernel(const int* __restrict__ masks, float* __restrict__ elas)
{
    const float ETAB[5] = {0.05f, 0.12f, 0.08f, 0.15f, 0.1f};
    __shared__ int sums[NPTS][NC_];
    int b = blockIdx.x;
    int t = threadIdx.x;
    if (t < NPTS * NC_) {
        int pt = t / NC_, c = t - pt * NC_;
        int i = pt / 3, j = pt % 3;
        int yc = (i * (H_ - 1)) / 2;
        int xc = (j * (W_ - 1)) / 2;
        int y0 = yc - 2 < 0 ? 0 : yc - 2;
        int y1 = yc + 3 > H_ ? H_ : yc + 3;
        int x0 = xc - 2 < 0 ? 0 : xc - 2;
        int x1 = xc + 3 > W_ ? W_ : xc + 3;
        int s = 0;
        for (int y = y0; y < y1; ++y)
            for (int xx = x0; xx < x1; ++xx)
                s += masks[((size_t)b * NC_ + c) * HW_ + y * W_ + xx];
        sums[pt][c] = s;
    }
    __syncthreads();
    if (t < NPTS) {
        int best = -1, best_c = 0;
        #pragma unroll
        for (int c = 0; c < NC_; ++c) {
            int s = sums[t][c];
            if (s > best) { best = s; best_c = c; }  // strict >: first max (jnp.argmax)
        }
        elas[b * NPTS + t] = ETAB[best_c];
    }
}

// ---------------- Kernel 3: TPS weights via precomputed L^-1 ----------------
__global__ void solve_kernel(const float* __restrict__ elas,
                             const float* __restrict__ ng,
                             const float* __restrict__ nl,
                             LinvT Linv, float* __restrict__ wts)
{
    int tid = blockIdx.x * 64 + threadIdx.x;
    if (tid >= 2 * B_) return;
    int t = tid / B_, b = tid - t * B_;
    const float* noise = (t == 0) ? ng : nl;
    float disp[NPTS][2];
    #pragma unroll
    for (int k = 0; k < NPTS; ++k) {
        float e = elas[b * NPTS + k];
        disp[k][0] = noise[((size_t)b * NPTS + k) * 2 + 0] * e;
        disp[k][1] = noise[((size_t)b * NPTS + k) * 2 + 1] * e;
    }
    #pragma unroll
    for (int c = 0; c < 2; ++c) {
        float nb = (disp[1][c] + disp[7][c] + disp[3][c] + disp[5][c]) * 0.25f;
        disp[4][c] = 0.8f * disp[4][c] + 0.2f * nb;
    }
    float dst[NPTS][2];
    #pragma unroll
    for (int k = 0; k < NPTS; ++k) {
        dst[k][0] = (float)(k / 3 - 1) + disp[k][0];
        dst[k][1] = (float)(k % 3 - 1) + disp[k][1];
    }
    float* wout = wts + (size_t)tid * 24;
    #pragma unroll
    for (int r = 0; r < 12; ++r) {
        float a0 = 0.f, a1 = 0.f;
        #pragma unroll
        for (int k = 0; k < NPTS; ++k) {
            a0 += Linv.m[r][k] * dst[k][0];
            a1 += Linv.m[r][k] * dst[k][1];
        }
        wout[r * 2 + 0] = a0;
        wout[r * 2 + 1] = a1;
    }
}

// ---------------- Kernel 4: TPS warp + bilinear; u[9] computed once per pixel ---------
__device__ __forceinline__ float tap_val(int t, int b, int y, int xx,
    const float* __restrict__ x, const float* __restrict__ mixed,
    const int* __restrict__ masks, float lam, int pb, int fused)
{
    if (y < 0 || y > H_ - 1 || xx < 0 || xx > W_ - 1) return 0.f;
    size_t off = (size_t)y * W_ + xx;
    if (t == 1) return x[(size_t)b * HW_ + off];
    if (!fused) return mixed[(size_t)b * HW_ + off];
    float xv  = x[(size_t)b * HW_ + off];
    float xpv = x[(size_t)pb * HW_ + off];
    int s = 0, fg = 0;
    #pragma unroll
    for (int c = 0; c < NC_; ++c) {
        int m = masks[((size_t)b * NC_ + c) * HW_ + off];
        s += m; fg += (m == 1);
    }
    float bg = (s == 0) ? 1.f : 0.f;
    return bg * xv + (float)fg * (lam * xv + (1.f - lam) * xpv);
}

__global__ __launch_bounds__(256) void warp_kernel(
    const float* __restrict__ x, const float* __restrict__ mixed,
    const float* __restrict__ wts, float* __restrict__ out,
    const int* __restrict__ masks, const float* __restrict__ lam_p,
    const int* __restrict__ perm, int fused)
{
    int p = blockIdx.x * 256 + threadIdx.x;   // pixel index, grid.x = HW/256 = 144
    int h   = p / W_;
    int wpx = p - h * W_;
    float px = -1.f + 2.f * (float)wpx / (float)(W_ - 1);
    float py = -1.f + 2.f * (float)h   / (float)(H_ - 1);

    // TPS radial kernel values: depend only on pixel position (not batch/transform)
    float u[NPTS];
    #pragma unroll
    for (int k = 0; k < NPTS; ++k) {
        float cx = (float)(k / 3 - 1);
        float cy = (float)(k % 3 - 1);
        float dx = px - cx, dy = py - cy;
        float d2 = dx * dx + dy * dy;
        u[k] = 0.5f * d2 * __logf(d2 + EPS_);
    }

    float lam = lam_p[0];
    #pragma unroll 4
    for (int i = 0; i < CHUNK; ++i) {
        int combo = blockIdx.y * CHUNK + i;   // t*B + b; uniform across block
        int t = combo >> 7;
        int b = combo & (B_ - 1);
        const float* wt = wts + (size_t)combo * 24;

        float gx = wt[18] + px * wt[20] + py * wt[22];
        float gy = wt[19] + px * wt[21] + py * wt[23];
        #pragma unroll
        for (int k = 0; k < NPTS; ++k) {
            gx += u[k] * wt[k * 2 + 0];
            gy += u[k] * wt[k * 2 + 1];
        }

        float ix = (gx + 1.f) * 0.5f * (float)(W_ - 1);
        float iy = (gy + 1.f) * 0.5f * (float)(H_ - 1);
        float x0f = floorf(ix), y0f = floorf(iy);
        float wx1 = ix - x0f, wx0 = 1.f - wx1;
        float wy1 = iy - y0f, wy0 = 1.f - wy1;
        int x0 = (int)x0f, y0 = (int)y0f;

        int pb = perm[b];
        float v00 = tap_val(t, b, y0,     x0,     x, mixed, masks, lam, pb, fused);
        float v01 = tap_val(t, b, y0,     x0 + 1, x, mixed, masks, lam, pb, fused);
        float v10 = tap_val(t, b, y0 + 1, x0,     x, mixed, masks, lam, pb, fused);
        float v11 = tap_val(t, b, y0 + 1, x0 + 1, x, mixed, masks, lam, pb, fused);

        out[(size_t)combo * HW_ + p] =
            v00 * (wy0 * wx0) + v01 * (wy0 * wx1) + v10 * (wy1 * wx0) + v11 * (wy1 * wx1);
    }
}

// ---------------- Host: build constant L^-1 (first 9 columns) in double ----------------
static void build_linv(LinvT* out)
{
    double srcp[NPTS][2];
    for (int k = 0; k < NPTS; ++k) {
        srcp[k][0] = (double)(k / 3) - 1.0;
        srcp[k][1] = (double)(k % 3) - 1.0;
    }
    double A[12][24];
    for (int r = 0; r < 12; ++r)
        for (int c = 0; c < 24; ++c) A[r][c] = 0.0;
    for (int i = 0; i < NPTS; ++i) {
        for (int j = 0; j < NPTS; ++j) {
            double dx = srcp[i][0] - srcp[j][0];
            double dy = srcp[i][1] - srcp[j][1];
            double d2 = dx * dx + dy * dy;
            A[i][j] = 0.5 * d2 * log(d2 + 1e-8);
        }
        A[i][9]  = 1.0; A[i][10] = srcp[i][0]; A[i][11] = srcp[i][1];
        A[9][i]  = 1.0; A[10][i] = srcp[i][0]; A[11][i] = srcp[i][1];
    }
    for (int r = 0; r < 12; ++r) A[r][12 + r] = 1.0;
    for (int col = 0; col < 12; ++col) {
        int piv = col; double mx = fabs(A[col][col]);
        for (int r = col + 1; r < 12; ++r)
            if (fabs(A[r][col]) > mx) { mx = fabs(A[r][col]); piv = r; }
        if (piv != col)
            for (int c = 0; c < 24; ++c) { double tmp = A[col][c]; A[col][c] = A[piv][c]; A[piv][c] = tmp; }
        double d = A[col][col];
        for (int c = 0; c < 24; ++c) A[col][c] /= d;
        for (int r = 0; r < 12; ++r) {
            if (r == col) continue;
            double f = A[r][col];
            if (f != 0.0)
                for (int c = 0; c < 24; ++c) A[r][c] -= f * A[col][c];
        }
    }
    for (int r = 0; r < 12; ++r)
        for (int k = 0; k < NPTS; ++k)
            out->m[r][k] = (float)A[r][12 + k];
}

extern "C" void kernel_launch(void* const* d_in, const int* in_sizes, int n_in,
                              void* d_out, int out_size, void* d_ws, size_t ws_size,
                              hipStream_t stream)
{
    (void)in_sizes; (void)n_in; (void)out_size;
    const float* x     = (const float*)d_in[0];
    const int*   masks = (const int*)d_in[1];
    const float* lam   = (const float*)d_in[2];
    const int*   perm  = (const int*)d_in[3];
    const float* ng    = (const float*)d_in[4];
    const float* nl    = (const float*)d_in[5];
    float* out = (float*)d_out;

    char* ws = (char*)d_ws;
    float* elas  = (float*)ws;              // 128*9*4   = 4608 B
    float* wts   = (float*)(ws + 8192);     // 2*128*24*4 = 24576 B
    float* mixed = (float*)(ws + 40960);    // B*HW*4    = 18.9 MB
    size_t need = 40960 + (size_t)B_ * HW_ * sizeof(float);
    int fused = (ws_size < need) ? 1 : 0;

    LinvT Linv;
    build_linv(&Linv);

    if (!fused) {
        int total4 = B_ * HW_ / 4;
        mixup_kernel<<<(total4 + 255) / 256, 256, 0, stream>>>(x, masks, lam, perm, mixed);
    }
    elas_kernel<<<B_, 64, 0, stream>>>(masks, elas);
    solve_kernel<<<(2 * B_ + 63) / 64, 64, 0, stream>>>(elas, ng, nl, Linv, wts);

    dim3 wgrid(HW_ / 256, (2 * B_) / CHUNK);
    warp_kernel<<<wgrid, 256, 0, stream>>>(x, mixed, wts, out, masks, lam, perm, fused);
}